// Round 13
// baseline (90.650 us; speedup 1.0000x reference)
//
#include <hip/hip_runtime.h>

#define GRP   8
#define FO    256
#define CIN   512
#define PTILE 16
#define XROW  520          // u16 per staged x row (512 + 8 pad)
#define NTILE 1568         // 25088 / 16
#define GRIDB 256

typedef __attribute__((ext_vector_type(8))) short bf16x8;
typedef __attribute__((ext_vector_type(4))) float f32x4;

__device__ __forceinline__ unsigned f2bu(float f) {
    unsigned u = __float_as_uint(f);
    return (u + 0x7FFFu + ((u >> 16) & 1u)) >> 16;   // RNE to bf16 (validated R1)
}
__device__ __forceinline__ short f2b(float f) { return (short)f2bu(f); }
__device__ __forceinline__ float sigmoidf_(float b) {
    return 1.0f / (1.0f + __expf(-b));
}
__device__ __forceinline__ float dot4(f32x4 a, f32x4 b) {
    return fmaf(a[0], b[0], fmaf(a[1], b[1], fmaf(a[2], b[2], a[3] * b[3])));
}

// ---- pre-kernel: repack kernels fp32 [g][p][f] -> bf16 MFMA A-frag order ----
// wpk[(((g*16+t)*2+kb)*64+lane)*8+j] = w[g][ p=kb*32+(lane>>4)*8+j ][ f=t*16+(lane&15) ]
__global__ void repack_w(const float* __restrict__ wk, unsigned short* __restrict__ wpk) {
    int id = blockIdx.x * 256 + threadIdx.x;      // 0 .. 131071
    int j    = id & 7;
    int lane = (id >> 3) & 63;
    int kb   = (id >> 9) & 1;
    int t    = (id >> 10) & 15;
    int g    = id >> 14;
    int p = kb * 32 + (lane >> 4) * 8 + j;
    int f = t * 16 + (lane & 15);
    wpk[id] = (unsigned short)f2bu(wk[(g * 64 + p) * FO + f]);
}

__global__ __launch_bounds__(1024, 1)
void dynroute_pers(const float* __restrict__ x, const unsigned short* __restrict__ wpk,
                   const float* __restrict__ bias, float* __restrict__ out) {
    __shared__ unsigned short xs[2][PTILE * XROW];  // 32.5 KB double-buffered x
    __shared__ float part_s[16][PTILE][8];          // [wave][pos][g], 8 KB
    __shared__ float alpha1_s[PTILE][8];
    __shared__ float alpha2_s[PTILE][8];

    const int tid  = threadIdx.x;
    const int lane = tid & 63;
    const int wave = tid >> 6;                // 0..15 == f-tile t
    const int pos  = lane & 15;
    const int lq   = lane >> 4;               // 0..3
    const int bid  = blockIdx.x;
    const int niter = (bid < NTILE - 6 * GRIDB) ? 7 : 6;   // 32 blocks do 7

    // ---- prologue: stage tile bid -> xs[0]; prefetch tile bid+GRIDB -------
    {
        const float* p = x + ((size_t)(bid * PTILE + wave)) * CIN + lane * 8;
        const float4 u0 = *reinterpret_cast<const float4*>(p);
        const float4 u1 = *reinterpret_cast<const float4*>(p + 4);
        bf16x8 v;
        v[0] = f2b(u0.x); v[1] = f2b(u0.y); v[2] = f2b(u0.z); v[3] = f2b(u0.w);
        v[4] = f2b(u1.x); v[5] = f2b(u1.y); v[6] = f2b(u1.z); v[7] = f2b(u1.w);
        *reinterpret_cast<bf16x8*>(&xs[0][wave * XROW + lane * 8]) = v;
    }
    float4 ra, rb;
    {
        const float* p = x + ((size_t)((bid + GRIDB) * PTILE + wave)) * CIN + lane * 8;
        ra = *reinterpret_cast<const float4*>(p);
        rb = *reinterpret_cast<const float4*>(p + 4);
    }
    __syncthreads();   // B0

    for (int i = 0; i < niter; ++i) {
        const int tile = bid + i * GRIDB;
        const int buf  = i & 1;

        // ---------------- MFMA: con[pos][f=wave*16+lq*4+r], 8 g ------------
        f32x4 acc[GRP];
        {
            const unsigned short* wb = wpk + wave * 1024 + lane * 8;
            const unsigned short* xrow = &xs[buf][pos * XROW];
            #pragma unroll
            for (int g = 0; g < GRP; ++g) {
                const bf16x8 wf0 = *reinterpret_cast<const bf16x8*>(wb + g * 16384);
                const bf16x8 wf1 = *reinterpret_cast<const bf16x8*>(wb + g * 16384 + 512);
                const bf16x8 xf0 = *reinterpret_cast<const bf16x8*>(&xrow[g * 64 + lq * 8]);
                const bf16x8 xf1 = *reinterpret_cast<const bf16x8*>(&xrow[g * 64 + 32 + lq * 8]);
                f32x4 a = {0.f, 0.f, 0.f, 0.f};
                a = __builtin_amdgcn_mfma_f32_16x16x32_bf16(wf0, xf0, a, 0, 0, 0);
                a = __builtin_amdgcn_mfma_f32_16x16x32_bf16(wf1, xf1, a, 0, 0, 0);
                acc[g] = a;
            }
        }

        // ---------------- routing round 1: d1[g] = <con_g, S> --------------
        {
            f32x4 S = acc[0];
            #pragma unroll
            for (int g = 1; g < GRP; ++g) S += acc[g];
            float d1[GRP];
            #pragma unroll
            for (int g = 0; g < GRP; ++g) d1[g] = dot4(acc[g], S);
            #pragma unroll
            for (int g = 0; g < GRP; ++g) {
                d1[g] += __shfl_xor(d1[g], 16, 64);
                d1[g] += __shfl_xor(d1[g], 32, 64);
            }
            if (lq == 0) {
                float4 v0 = {d1[0], d1[1], d1[2], d1[3]};
                float4 v1 = {d1[4], d1[5], d1[6], d1[7]};
                *reinterpret_cast<float4*>(&part_s[wave][pos][0]) = v0;
                *reinterpret_cast<float4*>(&part_s[wave][pos][4]) = v1;
            }
        }
        __syncthreads();   // B1

        float b1r = 0.f;
        if (tid < 128) {       // thread handles (pos = tid>>3, g = tid&7)
            const int rp = tid >> 3, rg = tid & 7;
            float s = 0.f;
            #pragma unroll
            for (int w = 0; w < 16; ++w) s += part_s[w][rp][rg];
            b1r = 0.5f * s;
            alpha1_s[rp][rg] = sigmoidf_(b1r);
        }
        __syncthreads();   // B2

        // ---------------- routing round 2: d2[g] = <con_g, S_alpha> --------
        {
            f32x4 sa = {0.f, 0.f, 0.f, 0.f};
            #pragma unroll
            for (int g = 0; g < GRP; ++g)
                sa = alpha1_s[pos][g] * acc[g] + sa;
            float d2[GRP];
            #pragma unroll
            for (int g = 0; g < GRP; ++g) d2[g] = dot4(acc[g], sa);
            #pragma unroll
            for (int g = 0; g < GRP; ++g) {
                d2[g] += __shfl_xor(d2[g], 16, 64);
                d2[g] += __shfl_xor(d2[g], 32, 64);
            }
            if (lq == 0) {
                float4 v0 = {d2[0], d2[1], d2[2], d2[3]};
                float4 v1 = {d2[4], d2[5], d2[6], d2[7]};
                *reinterpret_cast<float4*>(&part_s[wave][pos][0]) = v0;
                *reinterpret_cast<float4*>(&part_s[wave][pos][4]) = v1;
            }
        }
        __syncthreads();   // B3

        // ---- stage tile i+1 into xs[buf^1] (acc-free temps) ∥ α2 reduce ---
        {
            bf16x8 v;
            v[0] = f2b(ra.x); v[1] = f2b(ra.y); v[2] = f2b(ra.z); v[3] = f2b(ra.w);
            v[4] = f2b(rb.x); v[5] = f2b(rb.y); v[6] = f2b(rb.z); v[7] = f2b(rb.w);
            *reinterpret_cast<bf16x8*>(&xs[buf ^ 1][wave * XROW + lane * 8]) = v;
            int tn = tile + 2 * GRIDB;
            if (tn >= NTILE) tn = tile;
            const float* p = x + ((size_t)(tn * PTILE + wave)) * CIN + lane * 8;
            ra = *reinterpret_cast<const float4*>(p);
            rb = *reinterpret_cast<const float4*>(p + 4);
        }
        if (tid < 128) {
            const int rp = tid >> 3, rg = tid & 7;
            float s = 0.f;
            #pragma unroll
            for (int w = 0; w < 16; ++w) s += part_s[w][rp][rg];
            alpha2_s[rp][rg] = sigmoidf_(b1r + s);
        }
        __syncthreads();   // B4  (alpha2 ready AND next xs staged)

        // ---------------- epilogue: out = sum_g alpha2[g]*con_g + bias -----
        {
            const float4 bb = *reinterpret_cast<const float4*>(bias + wave * 16 + lq * 4);
            f32x4 o = {bb.x, bb.y, bb.z, bb.w};
            #pragma unroll
            for (int g = 0; g < GRP; ++g)
                o = alpha2_s[pos][g] * acc[g] + o;
            *reinterpret_cast<float4*>(
                out + ((size_t)(tile * PTILE + pos)) * FO + wave * 16 + lq * 4) =
                *reinterpret_cast<float4*>(&o);
        }
    }
}

extern "C" void kernel_launch(void* const* d_in, const int* in_sizes, int n_in,
                              void* d_out, int out_size, void* d_ws, size_t ws_size,
                              hipStream_t stream) {
    const float* x    = (const float*)d_in[0];
    const float* wk   = (const float*)d_in[1];
    const float* bias = (const float*)d_in[2];
    float* out        = (float*)d_out;
    unsigned short* wpk = (unsigned short*)d_ws;   // 256 KB of workspace

    hipLaunchKernelGGL(repack_w, dim3(512), dim3(256), 0, stream, wk, wpk);
    hipLaunchKernelGGL(dynroute_pers, dim3(GRIDB), dim3(1024), 0, stream,
                       x, wpk, bias, out);
}